// Round 10
// baseline (371.514 us; speedup 1.0000x reference)
//
#include <hip/hip_runtime.h>
#include <hip/hip_bf16.h>
#include <hip/hip_fp16.h>

#define N_NODES 50000
#define N_EDGES 500000
#define F_DIM   128
#define N_REL   8
#define N_LAYERS 2
#define NEG_SLOPE 0.2f

#define NBLK_N ((N_NODES + 255) / 256)   // 196 blocks over nodes

typedef short bf16x8 __attribute__((ext_vector_type(8)));
typedef float f32x4  __attribute__((ext_vector_type(4)));

// ---------------- helpers ----------------

__device__ inline short bfbits(float x) {
    __hip_bfloat16 h = __float2bfloat16(x);
    return *reinterpret_cast<short*>(&h);
}
__device__ inline float bf2f(short s) {
    unsigned u = ((unsigned)(unsigned short)s) << 16;
    return __uint_as_float(u);
}
__device__ inline float lrelu(float l) { return (l > 0.f) ? l : NEG_SLOPE * l; }

// ---------------- H prep: fp32 [N,128] -> Hh/Hl bf16 split (row-major) ------
__global__ __launch_bounds__(256) void prep_h(const float* __restrict__ H,
                                              short* __restrict__ Hh,
                                              short* __restrict__ Hl) {
    const size_t i8 = (size_t)blockIdx.x * 256 + threadIdx.x;   // 8-elem group
    if (i8 >= (size_t)N_NODES * F_DIM / 8) return;
    const float* src = H + i8 * 8;
    float av[8];
    *(float4*)(av)     = *(const float4*)(src);
    *(float4*)(av + 4) = *(const float4*)(src + 4);
    alignas(16) short hb[8];
    alignas(16) short lb[8];
#pragma unroll
    for (int j = 0; j < 8; ++j) {
        short h = bfbits(av[j]);
        hb[j] = h;
        lb[j] = bfbits(av[j] - bf2f(h));
    }
    *(uint4*)(Hh + i8 * 8) = *(const uint4*)hb;
    *(uint4*)(Hl + i8 * 8) = *(const uint4*)lb;
}

// ---------------- W prep: W[l,r,f,g] fp32 -> Wh/Wl[l,r,g,f] bf16 split -------
__global__ __launch_bounds__(256) void prep_w(const float* __restrict__ W,
                                              short* __restrict__ Wh,
                                              short* __restrict__ Wl) {
    __shared__ float tile[64][F_DIM + 1];
    const int mat = blockIdx.x;                      // l*N_REL + r
    const float* src = W + (size_t)mat * F_DIM * F_DIM;
    const int t = threadIdx.x;
    for (int hf = 0; hf < 2; ++hf) {
#pragma unroll
        for (int i = 0; i < 8; ++i) {
            int idx = t + i * 256;
            int f = idx >> 5, c4 = idx & 31;
            float4 v = *(const float4*)(src + (size_t)(hf * 64 + f) * F_DIM + c4 * 4);
            *(float4*)&tile[f][c4 * 4] = v;
        }
        __syncthreads();
        int g = t >> 1, fs = (t & 1) * 32;
        for (int c = 0; c < 4; ++c) {
            alignas(16) short th[8];
            alignas(16) short tl[8];
#pragma unroll
            for (int j = 0; j < 8; ++j) {
                float x = tile[fs + c * 8 + j][g];
                short hb = bfbits(x);
                th[j] = hb;
                tl[j] = bfbits(x - bf2f(hb));
            }
            size_t o = ((size_t)mat * F_DIM + g) * F_DIM + hf * 64 + fs + c * 8;
            *(uint4*)(Wh + o) = *(const uint4*)th;
            *(uint4*)(Wl + o) = *(const uint4*)tl;
        }
        __syncthreads();
    }
}

// ---------------- A-stationary MFMA GEMM (round-8 known-good) ---------------
// grid (391, 2), 512 threads (8 waves). Wave w owns rows rb0 + w*16 .. +15
// with split-A pinned in VGPRs across 4 relations (blockIdx.y picks which 4).
// W cycles through 64 KB XOR-swizzled LDS. xw stored COLUMN-PERMUTED:
//   xw'[row][ln*8 + t] = C[row][t*16 + ln]   (16B uint4 stores per lane)
// agg maps position p -> col (p&7)*16 + (p>>3).
#define GBM 128
#define RGRP 4
__global__ __launch_bounds__(512, 2) void gemm_xw(const short* __restrict__ Hh,
                                                  const short* __restrict__ Hl,
                                                  const short* __restrict__ Wh,
                                                  const short* __restrict__ Wl,
                                                  const float* __restrict__ qv_g,
                                                  const float* __restrict__ kv_g,
                                                  __half* __restrict__ xw,
                                                  float* __restrict__ a_q,
                                                  float* __restrict__ a_k) {
    __shared__ short lds[2 * F_DIM * F_DIM];   // 64 KB, [hi|lo][col][f] swizzled
    const int rb0 = blockIdx.x * GBM;
    const int r0  = blockIdx.y * RGRP;
    const int tid = threadIdx.x;
    const int lane = tid & 63, w = tid >> 6;
    const int q = lane >> 4, ln = lane & 15;

    // pinned A fragments for this lane's row
    const int arow_raw = rb0 + w * 16 + ln;
    const int arow = (arow_raw < N_NODES) ? arow_raw : (N_NODES - 1);
    bf16x8 Ah[4], Al[4];
    {
        const short* hph = Hh + (size_t)arow * F_DIM;
        const short* hpl = Hl + (size_t)arow * F_DIM;
#pragma unroll
        for (int ks = 0; ks < 4; ++ks) {
            Ah[ks] = *(const bf16x8*)(hph + ks * 32 + q * 8);
            Al[ks] = *(const bf16x8*)(hpl + ks * 32 + q * 8);
        }
    }

    for (int rr = 0; rr < RGRP; ++rr) {
        const int r = r0 + rr;
        __syncthreads();   // prev-relation LDS reads done
        // stage split-W[r]: 4096 16B chunks, 8 per thread, XOR-swizzled
        {
            const short* s0 = Wh + (size_t)r * F_DIM * F_DIM;
            const short* s1 = Wl + (size_t)r * F_DIM * F_DIM;
#pragma unroll
            for (int a = 0; a < 2; ++a) {
                const short* src = a ? s1 : s0;
#pragma unroll
                for (int i = 0; i < 4; ++i) {
                    int chunk = tid + i * 512;           // [0, 2048)
                    int g = chunk >> 4, c8 = chunk & 15;
                    uint4 v = *(const uint4*)(src + g * F_DIM + c8 * 8);
                    *(uint4*)(lds + a * 16384 + g * F_DIM + ((c8 ^ (g & 15)) * 8)) = v;
                }
            }
        }
        __syncthreads();

        f32x4 acc[8];
#pragma unroll
        for (int t = 0; t < 8; ++t) acc[t] = (f32x4)(0.f);
#pragma unroll
        for (int ks = 0; ks < 4; ++ks) {
            const int j = ks * 4 + q;                    // 16B chunk index along f
            bf16x8 Bh[8], Bl[8];
#pragma unroll
            for (int t = 0; t < 8; ++t) {
                const int col = t * 16 + ln;             // col & 15 == ln
                Bh[t] = *(const bf16x8*)(lds +         col * F_DIM + ((j ^ ln) << 3));
                Bl[t] = *(const bf16x8*)(lds + 16384 + col * F_DIM + ((j ^ ln) << 3));
            }
            // 8 independent chains per pass
#pragma unroll
            for (int t = 0; t < 8; ++t)
                acc[t] = __builtin_amdgcn_mfma_f32_16x16x32_bf16(Ah[ks], Bh[t], acc[t], 0, 0, 0);
#pragma unroll
            for (int t = 0; t < 8; ++t)
                acc[t] = __builtin_amdgcn_mfma_f32_16x16x32_bf16(Ah[ks], Bl[t], acc[t], 0, 0, 0);
#pragma unroll
            for (int t = 0; t < 8; ++t)
                acc[t] = __builtin_amdgcn_mfma_f32_16x16x32_bf16(Al[ks], Bh[t], acc[t], 0, 0, 0);
        }

        // epilogue: permuted 16B stores + in-wave q/k dots (no atomics)
        float qvl[8], kvl[8];
#pragma unroll
        for (int t = 0; t < 8; ++t) {
            qvl[t] = qv_g[t * 16 + ln];
            kvl[t] = kv_g[t * 16 + ln];
        }
        float pq[4], pk[4];
#pragma unroll
        for (int reg = 0; reg < 4; ++reg) {
            const int row = rb0 + w * 16 + q * 4 + reg;
            alignas(16) unsigned short hs[8];
            float sq = 0.f, sk = 0.f;
#pragma unroll
            for (int t = 0; t < 8; ++t) {
                float v = acc[t][reg];
                __half hv = __float2half(v);
                hs[t] = *reinterpret_cast<unsigned short*>(&hv);
                sq = fmaf(v, qvl[t], sq);
                sk = fmaf(v, kvl[t], sk);
            }
            if (row < N_NODES)
                *(uint4*)(xw + ((size_t)r * N_NODES + row) * F_DIM + ln * 8) = *(const uint4*)hs;
            pq[reg] = sq; pk[reg] = sk;
        }
#pragma unroll
        for (int reg = 0; reg < 4; ++reg) {
#pragma unroll
            for (int m = 1; m <= 8; m <<= 1) {
                pq[reg] += __shfl_xor(pq[reg], m);
                pk[reg] += __shfl_xor(pk[reg], m);
            }
        }
        if (ln == 0) {
#pragma unroll
            for (int reg = 0; reg < 4; ++reg) {
                const int row = rb0 + w * 16 + q * 4 + reg;
                if (row < N_NODES) {
                    a_q[r * N_NODES + row] = pq[reg];
                    a_k[r * N_NODES + row] = pk[reg];
                }
            }
        }
    }
}

// ---------------- CSR build ----------------

__global__ __launch_bounds__(256) void count_kernel(const int* __restrict__ dstp,
                                                    int* __restrict__ cnt) {
    int e = blockIdx.x * 256 + threadIdx.x;
    if (e < N_EDGES) atomicAdd(cnt + dstp[e], 1);
}

__global__ __launch_bounds__(256) void block_sum_kernel(const int* __restrict__ cnt,
                                                        int* __restrict__ partial) {
    __shared__ int s[256];
    int idx = blockIdx.x * 256 + threadIdx.x;
    int v = (idx < N_NODES) ? cnt[idx] : 0;
    s[threadIdx.x] = v;
    __syncthreads();
    for (int off = 128; off > 0; off >>= 1) {
        if (threadIdx.x < off) s[threadIdx.x] += s[threadIdx.x + off];
        __syncthreads();
    }
    if (threadIdx.x == 0) partial[blockIdx.x] = s[0];
}

__global__ __launch_bounds__(256) void scan_partials_kernel(int* __restrict__ partial,
                                                            int* __restrict__ row_ptr) {
    __shared__ int s[256];
    int t = threadIdx.x;
    int v = (t < NBLK_N) ? partial[t] : 0;
    s[t] = v;
    __syncthreads();
#pragma unroll
    for (int off = 1; off < 256; off <<= 1) {
        int x = (t >= off) ? s[t - off] : 0;
        __syncthreads();
        s[t] += x;
        __syncthreads();
    }
    if (t < NBLK_N) partial[t] = s[t] - v;
    if (t == 0) row_ptr[N_NODES] = N_EDGES;
}

__global__ __launch_bounds__(256) void scan_block_kernel(const int* __restrict__ cnt,
                                                         const int* __restrict__ partial,
                                                         int* __restrict__ row_ptr) {
    __shared__ int s[256];
    int t = threadIdx.x;
    int idx = blockIdx.x * 256 + t;
    int v = (idx < N_NODES) ? cnt[idx] : 0;
    s[t] = v;
    __syncthreads();
#pragma unroll
    for (int off = 1; off < 256; off <<= 1) {
        int x = (t >= off) ? s[t - off] : 0;
        __syncthreads();
        s[t] += x;
        __syncthreads();
    }
    if (idx < N_NODES) row_ptr[idx] = partial[blockIdx.x] + s[t] - v;
}

__global__ __launch_bounds__(256) void scatter_kernel(const int* __restrict__ srcp,
                                                      const int* __restrict__ dstp,
                                                      const int* __restrict__ etp,
                                                      const int* __restrict__ row_ptr,
                                                      int* __restrict__ cursor,
                                                      unsigned* __restrict__ sorted) {
    int e = blockIdx.x * 256 + threadIdx.x;
    if (e >= N_EDGES) return;
    int d = dstp[e];
    int pos = atomicAdd(cursor + d, 1);
    sorted[row_ptr[d] + pos] = (unsigned)srcp[e] | ((unsigned)etp[e] << 16);
}

// ---------------- fused softmax + aggregate + bias + relu ----------------
// xw is column-permuted: position p holds col (p&7)*16 + (p>>3).
__device__ inline void accum8(float* acc, uint4 v, float a) {
    const __half2* h2 = reinterpret_cast<const __half2*>(&v);
#pragma unroll
    for (int t = 0; t < 4; ++t) {
        float2 f = __half22float2(h2[t]);
        acc[t * 2]     = fmaf(a, f.x, acc[t * 2]);
        acc[t * 2 + 1] = fmaf(a, f.y, acc[t * 2 + 1]);
    }
}
__device__ inline const uint4* xwrow(const __half* xw, unsigned p, int ln) {
    return (const uint4*)(xw + (((size_t)(p >> 16)) * N_NODES + (p & 0xffff)) * F_DIM + ln * 8);
}

__global__ __launch_bounds__(256) void agg_fused(const __half* __restrict__ xw,
                                                 const float* __restrict__ a_q,
                                                 const float* __restrict__ a_k,
                                                 const int* __restrict__ row_ptr,
                                                 const unsigned* __restrict__ sorted,
                                                 const float* __restrict__ bias,
                                                 float* __restrict__ out) {
    const int lane = threadIdx.x & 63;
    const int wave = threadIdx.x >> 6;
    const int d = blockIdx.x * 4 + wave;
    if (d >= N_NODES) return;
    const int beg = row_ptr[d], end = row_ptr[d + 1];
    const int cnt = end - beg;
    const int g = lane >> 4, ln = lane & 15;   // 4 edge-groups x 16 col-lanes

    if (cnt <= 64) {
        // softmax: one edge per lane, fully in registers.
        // lanes >= cnt carry p=0 (a valid dummy row) and alpha=0, so the
        // gather loop below needs NO masking: dummy terms contribute 0.
        unsigned p = 0;
        float l = -3.4e38f;
        if (lane < cnt) {
            p = sorted[beg + lane];
            int s = p & 0xffff, t = p >> 16;
            l = lrelu(a_q[t * N_NODES + d] + a_k[t * N_NODES + s]);
        }
        float m = l;
#pragma unroll
        for (int off = 32; off > 0; off >>= 1) m = fmaxf(m, __shfl_xor(m, off));
        float ex = (lane < cnt) ? __expf(l - m) : 0.f;
        float dsum = ex;
#pragma unroll
        for (int off = 32; off > 0; off >>= 1) dsum += __shfl_xor(dsum, off);
        const float alpha = ex / (dsum + 1e-16f);

        // aggregation: 4 edges/group-step, 2 steps in flight, 16B/lane loads.
        // all shfl sources are < 64 by construction (i <= 56, +4+g <= 63).
        float acc[8] = {0, 0, 0, 0, 0, 0, 0, 0};
        for (int i = 0; i < cnt; i += 8) {
            unsigned p0 = __shfl(p, i + g);
            unsigned p1 = __shfl(p, i + 4 + g);
            float a0 = __shfl(alpha, i + g);
            float a1 = __shfl(alpha, i + 4 + g);
            uint4 v0 = *xwrow(xw, p0, ln);
            uint4 v1 = *xwrow(xw, p1, ln);
            accum8(acc, v0, a0);
            accum8(acc, v1, a1);
        }
        // cross-group reduction (sum over the 4 edge-groups)
#pragma unroll
        for (int t = 0; t < 8; ++t) {
            acc[t] += __shfl_xor(acc[t], 16);
            acc[t] += __shfl_xor(acc[t], 32);
        }
        if (g == 0) {
            // acc[t] holds position ln*8+t -> true col t*16+ln
#pragma unroll
            for (int t = 0; t < 8; ++t) {
                const int col = t * 16 + ln;
                out[(size_t)d * F_DIM + col] = fmaxf(acc[t] + bias[col], 0.f);
            }
        }
    } else {
        // rare high-degree fallback: per-lane 2-col scalar path
        const int p0 = lane * 2;
        const int c0 = (p0 & 7) * 16 + (p0 >> 3);
        const int c1 = c0 + 16;
        float2 acc = make_float2(bias[c0], bias[c1]);
        float m = -3.4e38f;
        for (int i = beg + lane; i < end; i += 64) {
            unsigned p = sorted[i];
            int s = p & 0xffff, t = p >> 16;
            m = fmaxf(m, lrelu(a_q[t * N_NODES + d] + a_k[t * N_NODES + s]));
        }
#pragma unroll
        for (int off = 32; off > 0; off >>= 1) m = fmaxf(m, __shfl_xor(m, off));
        float dsum = 0.f;
        for (int i = beg + lane; i < end; i += 64) {
            unsigned p = sorted[i];
            int s = p & 0xffff, t = p >> 16;
            dsum += __expf(lrelu(a_q[t * N_NODES + d] + a_k[t * N_NODES + s]) - m);
        }
#pragma unroll
        for (int off = 32; off > 0; off >>= 1) dsum += __shfl_xor(dsum, off);
        const float inv = 1.f / (dsum + 1e-16f);
        for (int i = beg; i < end; ++i) {
            unsigned p = sorted[i];
            int s = p & 0xffff, t = p >> 16;
            float alpha = __expf(lrelu(a_q[t * N_NODES + d] + a_k[t * N_NODES + s]) - m) * inv;
            const __half2 h2 = *((const __half2*)xw + (((size_t)(p >> 16)) * N_NODES + (p & 0xffff)) * (F_DIM / 2) + lane);
            float2 v = make_float2(__half2float(h2.x), __half2float(h2.y));
            acc.x = fmaf(alpha, v.x, acc.x);
            acc.y = fmaf(alpha, v.y, acc.y);
        }
        out[(size_t)d * F_DIM + c0] = fmaxf(acc.x, 0.f);
        out[(size_t)d * F_DIM + c1] = fmaxf(acc.y, 0.f);
    }
}

// ---------------- driver ----------------

extern "C" void kernel_launch(void* const* d_in, const int* in_sizes, int n_in,
                              void* d_out, int out_size, void* d_ws, size_t ws_size,
                              hipStream_t stream) {
    const float* x     = (const float*)d_in[0];
    const float* W     = (const float*)d_in[1];
    const float* att_q = (const float*)d_in[2];
    const float* att_k = (const float*)d_in[3];
    const float* bias  = (const float*)d_in[4];
    const int* ei      = (const int*)d_in[5];
    const int* etp     = (const int*)d_in[6];
    const int* srcp = ei;
    const int* dstp = ei + N_EDGES;
    float* out = (float*)d_out;
    char* ws   = (char*)d_ws;

    size_t off = 0;
    auto alloc = [&](size_t bytes) {
        void* p = ws + off;
        off = (off + bytes + 511) & ~(size_t)511;
        return p;
    };
    __half* xw       = (__half*)alloc((size_t)N_REL * N_NODES * F_DIM * sizeof(__half));
    float* a_q       = (float*)alloc((size_t)N_REL * N_NODES * sizeof(float));
    float* a_k       = (float*)alloc((size_t)N_REL * N_NODES * sizeof(float));
    int* cnt         = (int*)alloc((size_t)N_NODES * sizeof(int));
    int* row_ptr     = (int*)alloc(((size_t)N_NODES + 1) * sizeof(int));
    int* partial     = (int*)alloc(256 * sizeof(int));
    unsigned* sorted = (unsigned*)alloc((size_t)N_EDGES * sizeof(unsigned));
    short* Wh        = (short*)alloc((size_t)N_LAYERS * N_REL * F_DIM * F_DIM * sizeof(short));
    short* Wl        = (short*)alloc((size_t)N_LAYERS * N_REL * F_DIM * F_DIM * sizeof(short));
    short* Hh        = (short*)alloc((size_t)N_NODES * F_DIM * sizeof(short));
    short* Hl        = (short*)alloc((size_t)N_NODES * F_DIM * sizeof(short));

    prep_w<<<N_LAYERS * N_REL, 256, 0, stream>>>(W, Wh, Wl);
    hipMemsetAsync(cnt, 0, (size_t)N_NODES * 4, stream);
    count_kernel<<<(N_EDGES + 255) / 256, 256, 0, stream>>>(dstp, cnt);
    block_sum_kernel<<<NBLK_N, 256, 0, stream>>>(cnt, partial);
    scan_partials_kernel<<<1, 256, 0, stream>>>(partial, row_ptr);
    scan_block_kernel<<<NBLK_N, 256, 0, stream>>>(cnt, partial, row_ptr);
    hipMemsetAsync(cnt, 0, (size_t)N_NODES * 4, stream);
    scatter_kernel<<<(N_EDGES + 255) / 256, 256, 0, stream>>>(
        srcp, dstp, etp, row_ptr, cnt, sorted);

    const int grid_h = (N_NODES * F_DIM / 8 + 255) / 256;   // 3125
    const int grid_m = (N_NODES + GBM - 1) / GBM;           // 391
    for (int l = 0; l < N_LAYERS; ++l) {
        const float* H = (l == 0) ? x : out;
        prep_h<<<grid_h, 256, 0, stream>>>(H, Hh, Hl);
        gemm_xw<<<dim3(grid_m, N_REL / RGRP), 512, 0, stream>>>(
            Hh, Hl,
            Wh + (size_t)l * N_REL * F_DIM * F_DIM,
            Wl + (size_t)l * N_REL * F_DIM * F_DIM,
            att_q + l * F_DIM, att_k + l * F_DIM,
            xw, a_q, a_k);
        agg_fused<<<(N_NODES + 3) / 4, 256, 0, stream>>>(
            xw, a_q, a_k, row_ptr, sorted, bias + l * F_DIM, out);
    }
}

// Round 11
// 299.069 us; speedup vs baseline: 1.2422x; 1.2422x over previous
//
#include <hip/hip_runtime.h>
#include <hip/hip_bf16.h>
#include <hip/hip_fp16.h>

#define N_NODES 50000
#define N_EDGES 500000
#define F_DIM   128
#define N_REL   8
#define N_LAYERS 2
#define NEG_SLOPE 0.2f

#define NBLK_N ((N_NODES + 255) / 256)   // 196 blocks over nodes

typedef _Float16 half8 __attribute__((ext_vector_type(8)));
typedef float f32x4  __attribute__((ext_vector_type(4)));

// ---------------- helpers ----------------

__device__ inline float lrelu(float l) { return (l > 0.f) ? l : NEG_SLOPE * l; }

// ---------------- H prep: fp32 [N,128] -> fp16 (row-major) ------------------
__global__ __launch_bounds__(256) void prep_h(const float* __restrict__ H,
                                              _Float16* __restrict__ Hf) {
    const size_t i8 = (size_t)blockIdx.x * 256 + threadIdx.x;   // 8-elem group
    if (i8 >= (size_t)N_NODES * F_DIM / 8) return;
    const float* src = H + i8 * 8;
    float av[8];
    *(float4*)(av)     = *(const float4*)(src);
    *(float4*)(av + 4) = *(const float4*)(src + 4);
    alignas(16) _Float16 hb[8];
#pragma unroll
    for (int j = 0; j < 8; ++j) hb[j] = (_Float16)av[j];
    *(uint4*)(Hf + i8 * 8) = *(const uint4*)hb;
}

// ---------------- W prep: W[l,r,f,g] fp32 -> Wf[l,r,g,f] fp16 ---------------
__global__ __launch_bounds__(256) void prep_w(const float* __restrict__ W,
                                              _Float16* __restrict__ Wf) {
    __shared__ float tile[64][F_DIM + 1];
    const int mat = blockIdx.x;                      // l*N_REL + r
    const float* src = W + (size_t)mat * F_DIM * F_DIM;
    const int t = threadIdx.x;
    for (int hf = 0; hf < 2; ++hf) {
#pragma unroll
        for (int i = 0; i < 8; ++i) {
            int idx = t + i * 256;
            int f = idx >> 5, c4 = idx & 31;
            float4 v = *(const float4*)(src + (size_t)(hf * 64 + f) * F_DIM + c4 * 4);
            *(float4*)&tile[f][c4 * 4] = v;
        }
        __syncthreads();
        int g = t >> 1, fs = (t & 1) * 32;
        for (int c = 0; c < 4; ++c) {
            alignas(16) _Float16 th[8];
#pragma unroll
            for (int j = 0; j < 8; ++j) th[j] = (_Float16)tile[fs + c * 8 + j][g];
            size_t o = ((size_t)mat * F_DIM + g) * F_DIM + hf * 64 + fs + c * 8;
            *(uint4*)(Wf + o) = *(const uint4*)th;
        }
        __syncthreads();
    }
}

// ---------------- A-stationary fp16 MFMA GEMM, 32 rows/wave -----------------
// grid (391, 2), 256 threads (4 waves). Wave w owns rows rb0+w*32..+31 (two
// 16-row tiles, fp16 A pinned in VGPRs across 4 relations; blockIdx.y picks
// which 4). W[r] fp16 cycles through 32 KB XOR-swizzled LDS; each B read
// feeds 2 MFMAs. Single f16 MFMA per tile (no hi/lo split).
// xw stored COLUMN-PERMUTED: xw'[row][ln*8+t] = C[row][t*16+ln].
#define GBM 128
#define RGRP 4
__global__ __launch_bounds__(256, 2) void gemm_xw(const _Float16* __restrict__ Hf,
                                                  const _Float16* __restrict__ Wf,
                                                  const float* __restrict__ qv_g,
                                                  const float* __restrict__ kv_g,
                                                  __half* __restrict__ xw,
                                                  float* __restrict__ a_q,
                                                  float* __restrict__ a_k) {
    __shared__ _Float16 lds[F_DIM * F_DIM];    // 32 KB, [col][f] XOR-swizzled
    const int rb0 = blockIdx.x * GBM;
    const int r0  = blockIdx.y * RGRP;
    const int tid = threadIdx.x;
    const int lane = tid & 63, w = tid >> 6;
    const int q = lane >> 4, ln = lane & 15;

    // pinned fp16 A for this lane's two row-tiles
    half8 Af[2][4];
#pragma unroll
    for (int rt = 0; rt < 2; ++rt) {
        int row = rb0 + w * 32 + rt * 16 + ln;
        int ar = (row < N_NODES) ? row : (N_NODES - 1);
        const _Float16* hp = Hf + (size_t)ar * F_DIM;
#pragma unroll
        for (int ks = 0; ks < 4; ++ks)
            Af[rt][ks] = *(const half8*)(hp + ks * 32 + q * 8);
    }

    float qvl[8], kvl[8];
#pragma unroll
    for (int t = 0; t < 8; ++t) {
        qvl[t] = qv_g[t * 16 + ln];
        kvl[t] = kv_g[t * 16 + ln];
    }

    for (int rr = 0; rr < RGRP; ++rr) {
        const int r = r0 + rr;
        __syncthreads();   // prev-relation LDS reads done
        // stage W[r] fp16: 2048 16B chunks, 8 per thread, XOR-swizzled
        {
            const _Float16* src = Wf + (size_t)r * F_DIM * F_DIM;
#pragma unroll
            for (int i = 0; i < 8; ++i) {
                int chunk = tid + i * 256;               // [0, 2048)
                int gg = chunk >> 4, c8 = chunk & 15;
                uint4 v = *(const uint4*)(src + gg * F_DIM + c8 * 8);
                *(uint4*)(lds + gg * F_DIM + ((c8 ^ (gg & 15)) * 8)) = v;
            }
        }
        __syncthreads();

        f32x4 acc[2][8];
#pragma unroll
        for (int rt = 0; rt < 2; ++rt)
#pragma unroll
            for (int t = 0; t < 8; ++t) acc[rt][t] = (f32x4)(0.f);

#pragma unroll
        for (int ks = 0; ks < 4; ++ks) {
            const int jx = (((ks * 4 + q) ^ ln)) << 3;   // swizzled 16B chunk
            half8 Bf[8];
#pragma unroll
            for (int c = 0; c < 8; ++c)
                Bf[c] = *(const half8*)(lds + (c * 16 + ln) * F_DIM + jx);
            // 16 independent accumulator chains; each B feeds 2 MFMAs
#pragma unroll
            for (int c = 0; c < 8; ++c)
#pragma unroll
                for (int rt = 0; rt < 2; ++rt)
                    acc[rt][c] = __builtin_amdgcn_mfma_f32_16x16x32_f16(Af[rt][ks], Bf[c], acc[rt][c], 0, 0, 0);
        }

        // epilogue: permuted 16B stores + in-wave q/k dots (no atomics)
#pragma unroll
        for (int rt = 0; rt < 2; ++rt) {
            float pq[4], pk[4];
#pragma unroll
            for (int reg = 0; reg < 4; ++reg) {
                const int row = rb0 + w * 32 + rt * 16 + q * 4 + reg;
                alignas(16) unsigned short hs[8];
                float sq = 0.f, sk = 0.f;
#pragma unroll
                for (int t = 0; t < 8; ++t) {
                    float v = acc[rt][t][reg];
                    __half hv = __float2half(v);
                    hs[t] = *reinterpret_cast<unsigned short*>(&hv);
                    sq = fmaf(v, qvl[t], sq);
                    sk = fmaf(v, kvl[t], sk);
                }
                if (row < N_NODES)
                    *(uint4*)(xw + ((size_t)r * N_NODES + row) * F_DIM + ln * 8) = *(const uint4*)hs;
                pq[reg] = sq; pk[reg] = sk;
            }
#pragma unroll
            for (int reg = 0; reg < 4; ++reg) {
#pragma unroll
                for (int m = 1; m <= 8; m <<= 1) {
                    pq[reg] += __shfl_xor(pq[reg], m);
                    pk[reg] += __shfl_xor(pk[reg], m);
                }
            }
            if (ln == 0) {
#pragma unroll
                for (int reg = 0; reg < 4; ++reg) {
                    const int row = rb0 + w * 32 + rt * 16 + q * 4 + reg;
                    if (row < N_NODES) {
                        a_q[r * N_NODES + row] = pq[reg];
                        a_k[r * N_NODES + row] = pk[reg];
                    }
                }
            }
        }
    }
}

// ---------------- CSR build ----------------

__global__ __launch_bounds__(256) void count_kernel(const int* __restrict__ dstp,
                                                    int* __restrict__ cnt) {
    int e = blockIdx.x * 256 + threadIdx.x;
    if (e < N_EDGES) atomicAdd(cnt + dstp[e], 1);
}

__global__ __launch_bounds__(256) void block_sum_kernel(const int* __restrict__ cnt,
                                                        int* __restrict__ partial) {
    __shared__ int s[256];
    int idx = blockIdx.x * 256 + threadIdx.x;
    int v = (idx < N_NODES) ? cnt[idx] : 0;
    s[threadIdx.x] = v;
    __syncthreads();
    for (int off = 128; off > 0; off >>= 1) {
        if (threadIdx.x < off) s[threadIdx.x] += s[threadIdx.x + off];
        __syncthreads();
    }
    if (threadIdx.x == 0) partial[blockIdx.x] = s[0];
}

__global__ __launch_bounds__(256) void scan_partials_kernel(int* __restrict__ partial,
                                                            int* __restrict__ row_ptr) {
    __shared__ int s[256];
    int t = threadIdx.x;
    int v = (t < NBLK_N) ? partial[t] : 0;
    s[t] = v;
    __syncthreads();
#pragma unroll
    for (int off = 1; off < 256; off <<= 1) {
        int x = (t >= off) ? s[t - off] : 0;
        __syncthreads();
        s[t] += x;
        __syncthreads();
    }
    if (t < NBLK_N) partial[t] = s[t] - v;
    if (t == 0) row_ptr[N_NODES] = N_EDGES;
}

__global__ __launch_bounds__(256) void scan_block_kernel(const int* __restrict__ cnt,
                                                         const int* __restrict__ partial,
                                                         int* __restrict__ row_ptr) {
    __shared__ int s[256];
    int t = threadIdx.x;
    int idx = blockIdx.x * 256 + t;
    int v = (idx < N_NODES) ? cnt[idx] : 0;
    s[t] = v;
    __syncthreads();
#pragma unroll
    for (int off = 1; off < 256; off <<= 1) {
        int x = (t >= off) ? s[t - off] : 0;
        __syncthreads();
        s[t] += x;
        __syncthreads();
    }
    if (idx < N_NODES) row_ptr[idx] = partial[blockIdx.x] + s[t] - v;
}

__global__ __launch_bounds__(256) void scatter_kernel(const int* __restrict__ srcp,
                                                      const int* __restrict__ dstp,
                                                      const int* __restrict__ etp,
                                                      const int* __restrict__ row_ptr,
                                                      int* __restrict__ cursor,
                                                      unsigned* __restrict__ sorted) {
    int e = blockIdx.x * 256 + threadIdx.x;
    if (e >= N_EDGES) return;
    int d = dstp[e];
    int pos = atomicAdd(cursor + d, 1);
    sorted[row_ptr[d] + pos] = (unsigned)srcp[e] | ((unsigned)etp[e] << 16);
}

// ---------------- fused softmax + aggregate + bias + relu ----------------
// xw is column-permuted: position p holds col (p&7)*16 + (p>>3).
__device__ inline void accum8(float* acc, uint4 v, float a) {
    const __half2* h2 = reinterpret_cast<const __half2*>(&v);
#pragma unroll
    for (int t = 0; t < 4; ++t) {
        float2 f = __half22float2(h2[t]);
        acc[t * 2]     = fmaf(a, f.x, acc[t * 2]);
        acc[t * 2 + 1] = fmaf(a, f.y, acc[t * 2 + 1]);
    }
}
__device__ inline const uint4* xwrow(const __half* xw, unsigned p, int ln) {
    return (const uint4*)(xw + (((size_t)(p >> 16)) * N_NODES + (p & 0xffff)) * F_DIM + ln * 8);
}

__global__ __launch_bounds__(256) void agg_fused(const __half* __restrict__ xw,
                                                 const float* __restrict__ a_q,
                                                 const float* __restrict__ a_k,
                                                 const int* __restrict__ row_ptr,
                                                 const unsigned* __restrict__ sorted,
                                                 const float* __restrict__ bias,
                                                 float* __restrict__ out) {
    const int lane = threadIdx.x & 63;
    const int wave = threadIdx.x >> 6;
    const int d = blockIdx.x * 4 + wave;
    if (d >= N_NODES) return;
    const int beg = row_ptr[d], end = row_ptr[d + 1];
    const int cnt = end - beg;
    const int g = lane >> 4, ln = lane & 15;   // 4 edge-groups x 16 col-lanes

    if (cnt <= 64) {
        // softmax: one edge per lane; lanes >= cnt carry p=0 (valid dummy row)
        // and alpha=0, so the gather loop needs no masking.
        unsigned p = 0;
        float l = -3.4e38f;
        if (lane < cnt) {
            p = sorted[beg + lane];
            int s = p & 0xffff, t = p >> 16;
            l = lrelu(a_q[t * N_NODES + d] + a_k[t * N_NODES + s]);
        }
        float m = l;
#pragma unroll
        for (int off = 32; off > 0; off >>= 1) m = fmaxf(m, __shfl_xor(m, off));
        float ex = (lane < cnt) ? __expf(l - m) : 0.f;
        float dsum = ex;
#pragma unroll
        for (int off = 32; off > 0; off >>= 1) dsum += __shfl_xor(dsum, off);
        const float alpha = ex / (dsum + 1e-16f);

        float acc[8] = {0, 0, 0, 0, 0, 0, 0, 0};
        for (int i = 0; i < cnt; i += 8) {
            unsigned p0 = __shfl(p, i + g);
            unsigned p1 = __shfl(p, i + 4 + g);
            float a0 = __shfl(alpha, i + g);
            float a1 = __shfl(alpha, i + 4 + g);
            uint4 v0 = *xwrow(xw, p0, ln);
            uint4 v1 = *xwrow(xw, p1, ln);
            accum8(acc, v0, a0);
            accum8(acc, v1, a1);
        }
#pragma unroll
        for (int t = 0; t < 8; ++t) {
            acc[t] += __shfl_xor(acc[t], 16);
            acc[t] += __shfl_xor(acc[t], 32);
        }
        if (g == 0) {
#pragma unroll
            for (int t = 0; t < 8; ++t) {
                const int col = t * 16 + ln;
                out[(size_t)d * F_DIM + col] = fmaxf(acc[t] + bias[col], 0.f);
            }
        }
    } else {
        // rare high-degree fallback: per-lane 2-col scalar path
        const int p0 = lane * 2;
        const int c0 = (p0 & 7) * 16 + (p0 >> 3);
        const int c1 = c0 + 16;
        float2 acc = make_float2(bias[c0], bias[c1]);
        float m = -3.4e38f;
        for (int i = beg + lane; i < end; i += 64) {
            unsigned p = sorted[i];
            int s = p & 0xffff, t = p >> 16;
            m = fmaxf(m, lrelu(a_q[t * N_NODES + d] + a_k[t * N_NODES + s]));
        }
#pragma unroll
        for (int off = 32; off > 0; off >>= 1) m = fmaxf(m, __shfl_xor(m, off));
        float dsum = 0.f;
        for (int i = beg + lane; i < end; i += 64) {
            unsigned p = sorted[i];
            int s = p & 0xffff, t = p >> 16;
            dsum += __expf(lrelu(a_q[t * N_NODES + d] + a_k[t * N_NODES + s]) - m);
        }
#pragma unroll
        for (int off = 32; off > 0; off >>= 1) dsum += __shfl_xor(dsum, off);
        const float inv = 1.f / (dsum + 1e-16f);
        for (int i = beg; i < end; ++i) {
            unsigned p = sorted[i];
            int s = p & 0xffff, t = p >> 16;
            float alpha = __expf(lrelu(a_q[t * N_NODES + d] + a_k[t * N_NODES + s]) - m) * inv;
            const __half2 h2 = *((const __half2*)xw + (((size_t)(p >> 16)) * N_NODES + (p & 0xffff)) * (F_DIM / 2) + lane);
            float2 v = make_float2(__half2float(h2.x), __half2float(h2.y));
            acc.x = fmaf(alpha, v.x, acc.x);
            acc.y = fmaf(alpha, v.y, acc.y);
        }
        out[(size_t)d * F_DIM + c0] = fmaxf(acc.x, 0.f);
        out[(size_t)d * F_DIM + c1] = fmaxf(acc.y, 0.f);
    }
}

// ---------------- driver ----------------

extern "C" void kernel_launch(void* const* d_in, const int* in_sizes, int n_in,
                              void* d_out, int out_size, void* d_ws, size_t ws_size,
                              hipStream_t stream) {
    const float* x     = (const float*)d_in[0];
    const float* W     = (const float*)d_in[1];
    const float* att_q = (const float*)d_in[2];
    const float* att_k = (const float*)d_in[3];
    const float* bias  = (const float*)d_in[4];
    const int* ei      = (const int*)d_in[5];
    const int* etp     = (const int*)d_in[6];
    const int* srcp = ei;
    const int* dstp = ei + N_EDGES;
    float* out = (float*)d_out;
    char* ws   = (char*)d_ws;

    size_t off = 0;
    auto alloc = [&](size_t bytes) {
        void* p = ws + off;
        off = (off + bytes + 511) & ~(size_t)511;
        return p;
    };
    __half* xw       = (__half*)alloc((size_t)N_REL * N_NODES * F_DIM * sizeof(__half));
    float* a_q       = (float*)alloc((size_t)N_REL * N_NODES * sizeof(float));
    float* a_k       = (float*)alloc((size_t)N_REL * N_NODES * sizeof(float));
    int* cnt         = (int*)alloc((size_t)N_NODES * sizeof(int));
    int* row_ptr     = (int*)alloc(((size_t)N_NODES + 1) * sizeof(int));
    int* partial     = (int*)alloc(256 * sizeof(int));
    unsigned* sorted = (unsigned*)alloc((size_t)N_EDGES * sizeof(unsigned));
    _Float16* Wf     = (_Float16*)alloc((size_t)N_LAYERS * N_REL * F_DIM * F_DIM * sizeof(_Float16));
    _Float16* Hf     = (_Float16*)alloc((size_t)N_NODES * F_DIM * sizeof(_Float16));

    prep_w<<<N_LAYERS * N_REL, 256, 0, stream>>>(W, Wf);
    hipMemsetAsync(cnt, 0, (size_t)N_NODES * 4, stream);
    count_kernel<<<(N_EDGES + 255) / 256, 256, 0, stream>>>(dstp, cnt);
    block_sum_kernel<<<NBLK_N, 256, 0, stream>>>(cnt, partial);
    scan_partials_kernel<<<1, 256, 0, stream>>>(partial, row_ptr);
    scan_block_kernel<<<NBLK_N, 256, 0, stream>>>(cnt, partial, row_ptr);
    hipMemsetAsync(cnt, 0, (size_t)N_NODES * 4, stream);
    scatter_kernel<<<(N_EDGES + 255) / 256, 256, 0, stream>>>(
        srcp, dstp, etp, row_ptr, cnt, sorted);

    const int grid_h = (N_NODES * F_DIM / 8 + 255) / 256;   // 3125
    const int grid_m = (N_NODES + GBM - 1) / GBM;           // 391
    for (int l = 0; l < N_LAYERS; ++l) {
        const float* H = (l == 0) ? x : out;
        prep_h<<<grid_h, 256, 0, stream>>>(H, Hf);
        gemm_xw<<<dim3(grid_m, N_REL / RGRP), 256, 0, stream>>>(
            Hf, Wf + (size_t)l * N_REL * F_DIM * F_DIM,
            att_q + l * F_DIM, att_k + l * F_DIM,
            xw, a_q, a_k);
        agg_fused<<<(N_NODES + 3) / 4, 256, 0, stream>>>(
            xw, a_q, a_k, row_ptr, sorted, bias + l * F_DIM, out);
    }
}